// Round 5
// baseline (1198.076 us; speedup 1.0000x reference)
//
#include <hip/hip_runtime.h>
#include <math.h>

// Problem constants
#define NB 8
#define SEQ 1024
#define DM 512
#define NH 8
#define HDIM 64
#define DFF 2048
#define NLAYER 4
#define NTOK (NB * SEQ)   // 8192
#define QKVD 1536         // fused q|k|v row width

typedef __attribute__((ext_vector_type(8))) short bf16x8;
typedef __attribute__((ext_vector_type(4))) float f32x4;

__device__ __forceinline__ ushort f2bf(float f) {
    union { float f; unsigned u; } v; v.f = f;
    unsigned r = (v.u + 0x7FFF + ((v.u >> 16) & 1)) >> 16;  // RNE
    return (ushort)r;
}

// async global->LDS, 16B per lane (LDS dest must be wave-uniform base + lane*16)
__device__ __forceinline__ void async16(const void* g, void* l) {
    __builtin_amdgcn_global_load_lds(
        (const __attribute__((address_space(1))) unsigned int*)g,
        (__attribute__((address_space(3))) unsigned int*)l, 16, 0, 0);
}

// ---------------------------------------------------------------------------
// Positional encoding add
// ---------------------------------------------------------------------------
__global__ __launch_bounds__(256) void add_pos_kernel(const float* __restrict__ x,
                                                      float* __restrict__ out) {
    int idx4 = blockIdx.x * blockDim.x + threadIdx.x;
    int base = idx4 * 4;
    int d = base & (DM - 1);
    int s = (base >> 9) & (SEQ - 1);
    float4 v = *(const float4*)&x[base];
    float r[4] = {v.x, v.y, v.z, v.w};
#pragma unroll
    for (int i = 0; i < 4; i++) {
        int dd = d + i;
        float pe;
        if (dd < 256) {
            float inv = powf(10000.0f, 2.0f * (float)dd / 512.0f);
            pe = sinf((float)s / inv);
        } else {
            float inv = powf(10000.0f, 2.0f * (float)(dd - 256) / 512.0f);
            pe = cosf((float)s / inv);
        }
        r[i] += pe;
    }
    *(float4*)&out[base] = make_float4(r[0], r[1], r[2], r[3]);
}

// ---------------------------------------------------------------------------
// Weight convert+transpose: src fp32 [L][K][N] -> dst bf16 rows at
// dst + l*layerStride + (rowOff + n)*K + k
// ---------------------------------------------------------------------------
__global__ __launch_bounds__(256) void wtrans_kernel(const float* __restrict__ src,
                                                     ushort* __restrict__ dst,
                                                     int K, int N, int rowOff,
                                                     int layerStride) {
    __shared__ float tile[32][36];
    int l = blockIdx.z;
    int kb = blockIdx.y * 32, nb = blockIdx.x * 32;
    const float* s = src + (size_t)l * K * N;
    ushort* d = dst + (size_t)l * layerStride;
    int r = threadIdx.x >> 3, c4 = (threadIdx.x & 7) * 4;
    float4 v = *(const float4*)&s[(size_t)(kb + r) * N + nb + c4];
    *(float4*)&tile[r][c4] = v;
    __syncthreads();
    ushort4 o;
    o.x = f2bf(tile[c4 + 0][r]);
    o.y = f2bf(tile[c4 + 1][r]);
    o.z = f2bf(tile[c4 + 2][r]);
    o.w = f2bf(tile[c4 + 3][r]);
    *(ushort4*)&d[(size_t)(rowOff + nb + r) * K + kb + c4] = o;
}

// ---------------------------------------------------------------------------
// bf16 transpose of V slice of qkv: qkv[b*SEQ+s][1024+c] -> vT[b][c][s]
// ---------------------------------------------------------------------------
__global__ __launch_bounds__(256) void vtrans_kernel(const ushort* __restrict__ qkv,
                                                     ushort* __restrict__ vT) {
    __shared__ ushort tile[32][36];
    int b = blockIdx.z;
    int s0 = blockIdx.y * 32, c0 = blockIdx.x * 32;
    int r = threadIdx.x >> 3, q4 = (threadIdx.x & 7) * 4;
    *(ushort4*)&tile[r][q4] =
        *(const ushort4*)&qkv[(size_t)(b * SEQ + s0 + r) * QKVD + 1024 + c0 + q4];
    __syncthreads();
    ushort4 o;
    o.x = tile[q4 + 0][r];
    o.y = tile[q4 + 1][r];
    o.z = tile[q4 + 2][r];
    o.w = tile[q4 + 3][r];
    *(ushort4*)&vT[(size_t)(b * DM + c0 + r) * SEQ + s0 + q4] = o;
}

// ---------------------------------------------------------------------------
// LayerNorm fp32 in -> bf16 out. One wave per row, 4 rows/block.
// ---------------------------------------------------------------------------
__global__ __launch_bounds__(256) void ln_kernel(const float* __restrict__ x,
                                                 const float* __restrict__ g,
                                                 const float* __restrict__ bta,
                                                 ushort* __restrict__ out) {
    int w = threadIdx.x >> 6;
    int lane = threadIdx.x & 63;
    size_t row = (size_t)blockIdx.x * 4 + w;
    const float* xr = x + row * DM;
    float4 v0 = *(const float4*)&xr[lane * 4];
    float4 v1 = *(const float4*)&xr[256 + lane * 4];
    float sum = v0.x + v0.y + v0.z + v0.w + v1.x + v1.y + v1.z + v1.w;
#pragma unroll
    for (int off = 32; off > 0; off >>= 1) sum += __shfl_xor(sum, off, 64);
    float mu = sum * (1.0f / 512.0f);
    float d0[8] = {v0.x - mu, v0.y - mu, v0.z - mu, v0.w - mu,
                   v1.x - mu, v1.y - mu, v1.z - mu, v1.w - mu};
    float sq = 0.0f;
#pragma unroll
    for (int i = 0; i < 8; i++) sq = fmaf(d0[i], d0[i], sq);
#pragma unroll
    for (int off = 32; off > 0; off >>= 1) sq += __shfl_xor(sq, off, 64);
    float rs = rsqrtf(sq * (1.0f / 512.0f) + 1e-3f);
    float4 g0 = *(const float4*)&g[lane * 4];
    float4 g1 = *(const float4*)&g[256 + lane * 4];
    float4 b0 = *(const float4*)&bta[lane * 4];
    float4 b1 = *(const float4*)&bta[256 + lane * 4];
    ushort* orow = out + row * DM;
    ushort4 o0, o1;
    o0.x = f2bf(fmaf(d0[0] * rs, g0.x, b0.x));
    o0.y = f2bf(fmaf(d0[1] * rs, g0.y, b0.y));
    o0.z = f2bf(fmaf(d0[2] * rs, g0.z, b0.z));
    o0.w = f2bf(fmaf(d0[3] * rs, g0.w, b0.w));
    o1.x = f2bf(fmaf(d0[4] * rs, g1.x, b1.x));
    o1.y = f2bf(fmaf(d0[5] * rs, g1.y, b1.y));
    o1.z = f2bf(fmaf(d0[6] * rs, g1.z, b1.z));
    o1.w = f2bf(fmaf(d0[7] * rs, g1.w, b1.w));
    *(ushort4*)&orow[lane * 4] = o0;
    *(ushort4*)&orow[256 + lane * 4] = o1;
}

// ---------------------------------------------------------------------------
// bf16 MFMA GEMM. Tile 128x128, BK=32, 4 waves. Chunk-major LDS (conflict-free).
// Split-K via blockIdx.z (KSPLIT blocks share one C tile, fp32 atomicAdd).
// MODE: 0 = bf16 store; 1 = fp32 atomic +=; 2 = bias+relu -> bf16;
//       3 = bias (kb==0 only) + fp32 atomic +=
// ---------------------------------------------------------------------------
template <int MODE, int KSPLIT>
__global__ __launch_bounds__(256) void gemm_bf16(const ushort* __restrict__ A,
                                                 const ushort* __restrict__ Bt,
                                                 const float* __restrict__ bias,
                                                 void* __restrict__ Cv,
                                                 int M, int N, int K) {
    __shared__ __align__(16) ushort As[128 * 32];
    __shared__ __align__(16) ushort Bs[128 * 32];
    const int tid = threadIdx.x;
    const int lane = tid & 63;
    const int w = tid >> 6;
    const int m0 = blockIdx.y * 128, n0 = blockIdx.x * 128;
    const int kb = blockIdx.z;
    const int kchunk = K / KSPLIT;
    const int k0 = kb * kchunk, k1 = k0 + kchunk;
    const int wm = (w >> 1) * 64, wn = (w & 1) * 64;
    const int fm = lane & 15, fq = lane >> 4;

    f32x4 acc[4][4] = {};

    for (int kt = k0; kt < k1; kt += 32) {
        __syncthreads();
        // chunk-major [kc(4)][row(128)]: slot s -> kc = s>>7, row = s&127
#pragma unroll
        for (int u = 0; u < 2; u++) {
            int s = (w * 2 + u) * 64 + lane;
            int c = s >> 7, row = s & 127;
            async16(&A[(size_t)(m0 + row) * K + kt + c * 8], (char*)As + s * 16);
            async16(&Bt[(size_t)(n0 + row) * K + kt + c * 8], (char*)Bs + s * 16);
        }
        __syncthreads();
        bf16x8 af[4], bfr[4];
#pragma unroll
        for (int i = 0; i < 4; i++)
            af[i] = *(const bf16x8*)&As[(fq * 128 + wm + i * 16 + fm) * 8];
#pragma unroll
        for (int j = 0; j < 4; j++)
            bfr[j] = *(const bf16x8*)&Bs[(fq * 128 + wn + j * 16 + fm) * 8];
#pragma unroll
        for (int i = 0; i < 4; i++)
#pragma unroll
            for (int j = 0; j < 4; j++)
                acc[i][j] = __builtin_amdgcn_mfma_f32_16x16x32_bf16(
                    af[i], bfr[j], acc[i][j], 0, 0, 0);
    }

#pragma unroll
    for (int i = 0; i < 4; i++) {
#pragma unroll
        for (int j = 0; j < 4; j++) {
            int col = n0 + wn + j * 16 + fm;
#pragma unroll
            for (int r = 0; r < 4; r++) {
                int row = m0 + wm + i * 16 + fq * 4 + r;
                float vv = acc[i][j][r];
                if constexpr (MODE == 0) {
                    ((ushort*)Cv)[(size_t)row * N + col] = f2bf(vv);
                } else if constexpr (MODE == 1) {
                    atomicAdd((float*)Cv + (size_t)row * N + col, vv);
                } else if constexpr (MODE == 2) {
                    vv += bias[col];
                    vv = fmaxf(vv, 0.0f);
                    ((ushort*)Cv)[(size_t)row * N + col] = f2bf(vv);
                } else {
                    if (KSPLIT > 1 && kb == 0) vv += bias[col];
                    else if (KSPLIT == 1) vv += bias[col];
                    atomicAdd((float*)Cv + (size_t)row * N + col, vv);
                }
            }
        }
    }
}

// ---------------------------------------------------------------------------
// Flash attention, S^T formulation (unchanged from round 3).
// ---------------------------------------------------------------------------
__global__ __launch_bounds__(256) void attn_mfma(const ushort* __restrict__ QKV,
                                                 const ushort* __restrict__ Vt,
                                                 const int* __restrict__ mask,
                                                 ushort* __restrict__ O) {
    __shared__ __align__(16) ushort Kt[64 * 64];
    __shared__ __align__(16) ushort Vs[64 * 64];
    __shared__ __align__(16) ushort ps[4][16 * 72];  // per-wave P^T [q][key], stride 72
    __shared__ float mskf[64];

    const int tid = threadIdx.x, lane = tid & 63, w = tid >> 6;
    const int h = blockIdx.y, b = blockIdx.z;
    const int q0 = blockIdx.x * 64 + w * 16;
    const int fm = lane & 15, fq = lane >> 4;
    ushort* pw = &ps[w][0];

    // Q as B-fragment: lane: n = q0+fm, k = kk*32 + fq*8 + j
    bf16x8 qf[2];
#pragma unroll
    for (int kk = 0; kk < 2; kk++)
        qf[kk] = *(const bf16x8*)&QKV[(size_t)(b * SEQ + q0 + fm) * QKVD + h * HDIM +
                                      kk * 32 + fq * 8];

    f32x4 oacc[4] = {};   // O^T: col = q (fm), rows dim = nt*16 + fq*4 + r
    float mrow = -INFINITY, lrow = 0.0f;

    for (int j0 = 0; j0 < SEQ; j0 += 64) {
        __syncthreads();
#pragma unroll
        for (int u = 0; u < 2; u++) {
            int ch = tid + u * 256;            // 0..511
            int rrow = ch >> 3, c = ch & 7;
            const ushort* gk = &QKV[(size_t)(b * SEQ + j0 + rrow) * QKVD + 512 +
                                    h * HDIM + c * 8];
            *(uint4*)((char*)Kt + (rrow * 8 + (c ^ (rrow & 7))) * 16) = *(const uint4*)gk;
            const ushort* gv = &Vt[(size_t)((b * NH + h) * HDIM + rrow) * SEQ + j0 + c * 8];
            *(uint4*)((char*)Vs + (rrow * 8 + (c ^ (rrow & 7))) * 16) = *(const uint4*)gv;
        }
        if (tid < 64) mskf[tid] = mask[b * SEQ + j0 + tid] ? 1.0f : 0.0f;
        __syncthreads();

        // ---- S^T = K Q^T : lane holds q-col fm, keys nt*16 + fq*4 + r ----
        f32x4 sc[4] = {};
#pragma unroll
        for (int nt = 0; nt < 4; nt++) {
            int key = nt * 16 + fm;
#pragma unroll
            for (int kk = 0; kk < 2; kk++) {
                bf16x8 kf = *(const bf16x8*)((char*)Kt +
                            (key * 8 + ((kk * 4 + fq) ^ (key & 7))) * 16);
                sc[nt] = __builtin_amdgcn_mfma_f32_16x16x32_bf16(kf, qf[kk], sc[nt], 0, 0, 0);
            }
        }

        // ---- online softmax over the lane's 16 keys ----
        float sv[4][4];
        float mx = -INFINITY;
#pragma unroll
        for (int nt = 0; nt < 4; nt++)
#pragma unroll
            for (int r = 0; r < 4; r++) {
                sv[nt][r] = sc[nt][r] * 0.125f;
                mx = fmaxf(mx, sv[nt][r]);
            }
        mx = fmaxf(mx, __shfl_xor(mx, 16));
        mx = fmaxf(mx, __shfl_xor(mx, 32));
        float mn = fmaxf(mrow, mx);
        float alpha = __expf(mrow - mn);
        mrow = mn;

        float ls = 0.0f;
#pragma unroll
        for (int nt = 0; nt < 4; nt++) {
            f32x4 mv = *(const f32x4*)&mskf[nt * 16 + fq * 4];
#pragma unroll
            for (int r = 0; r < 4; r++) {
                float p = __expf(sv[nt][r] - mn) * mv[r];
                sv[nt][r] = p;
                ls += p;
            }
        }
        ls += __shfl_xor(ls, 16);
        ls += __shfl_xor(ls, 32);
        lrow = lrow * alpha + ls;

        // ---- P^T to per-wave LDS: pw[q=fm][key], trunc-to-bf16 packed ----
#pragma unroll
        for (int nt = 0; nt < 4; nt++) {
            union { float f; unsigned u; } a0, a1, a2, a3;
            a0.f = sv[nt][0]; a1.f = sv[nt][1]; a2.f = sv[nt][2]; a3.f = sv[nt][3];
            unsigned d0 = (a0.u >> 16) | (a1.u & 0xFFFF0000u);
            unsigned d1 = (a2.u >> 16) | (a3.u & 0xFFFF0000u);
            *(uint2*)&pw[fm * 72 + nt * 16 + fq * 4] = make_uint2(d0, d1);
        }

        // rescale O accumulator (alpha is per-lane scalar)
#pragma unroll
        for (int nt = 0; nt < 4; nt++)
#pragma unroll
            for (int r = 0; r < 4; r++) oacc[nt][r] *= alpha;

        // ---- O^T += V^T P^T ----
#pragma unroll
        for (int kk = 0; kk < 2; kk++) {
            bf16x8 pf = *(const bf16x8*)&pw[fm * 72 + kk * 32 + fq * 8];
#pragma unroll
            for (int nt = 0; nt < 4; nt++) {
                int dim = nt * 16 + fm;
                bf16x8 vf = *(const bf16x8*)((char*)Vs +
                            (dim * 8 + ((kk * 4 + fq) ^ (dim & 7))) * 16);
                oacc[nt] = __builtin_amdgcn_mfma_f32_16x16x32_bf16(vf, pf, oacc[nt], 0, 0, 0);
            }
        }
    }

    float inv = 1.0f / lrow;
#pragma unroll
    for (int nt = 0; nt < 4; nt++) {
        ushort4 o;
        o.x = f2bf(oacc[nt][0] * inv);
        o.y = f2bf(oacc[nt][1] * inv);
        o.z = f2bf(oacc[nt][2] * inv);
        o.w = f2bf(oacc[nt][3] * inv);
        *(ushort4*)&O[(size_t)(b * SEQ + q0 + fm) * DM + h * HDIM + nt * 16 + fq * 4] = o;
    }
}

// ---------------------------------------------------------------------------
extern "C" void kernel_launch(void* const* d_in, const int* in_sizes, int n_in,
                              void* d_out, int out_size, void* d_ws, size_t ws_size,
                              hipStream_t stream) {
    const float* x_in = (const float*)d_in[0];
    const int* mask   = (const int*)d_in[1];
    const float* Wq   = (const float*)d_in[2];
    const float* Wk   = (const float*)d_in[3];
    const float* Wv   = (const float*)d_in[4];
    const float* Wo   = (const float*)d_in[5];
    const float* ln1g = (const float*)d_in[6];
    const float* ln1b = (const float*)d_in[7];
    const float* ln2g = (const float*)d_in[8];
    const float* ln2b = (const float*)d_in[9];
    const float* W1   = (const float*)d_in[10];
    const float* b1   = (const float*)d_in[11];
    const float* W2   = (const float*)d_in[12];
    const float* b2   = (const float*)d_in[13];

    float* x = (float*)d_out;  // fp32 residual stream
    ushort* wsb = (ushort*)d_ws;
    const size_t U = 1048576;
    ushort* WqkvT = wsb;            // [L][1536][512]  (3U)
    ushort* WoT   = wsb + 3 * U;    // [L][512][512]   (1U)
    ushort* W1T   = wsb + 4 * U;    // [L][2048][512]  (4U)
    ushort* W2T   = wsb + 8 * U;    // [L][512][2048]  (4U)
    ushort* hb    = wsb + 12 * U;   // bf16 [8192][512]
    ushort* qkv   = wsb + 16 * U;   // bf16 [8192][1536] (12U)
    ushort* ob    = wsb + 28 * U;   // bf16 [8192][512]
    ushort* vTb   = wsb + 32 * U;   // bf16 [8][512][1024]
    ushort* f1b   = qkv;            // 16U alias (qkv+ob), dead during FFN

    // Weight convert+transpose (graph-safe: every launch)
    wtrans_kernel<<<dim3(16, 16, 4), 256, 0, stream>>>(Wq, WqkvT, 512, 512, 0, 786432);
    wtrans_kernel<<<dim3(16, 16, 4), 256, 0, stream>>>(Wk, WqkvT, 512, 512, 512, 786432);
    wtrans_kernel<<<dim3(16, 16, 4), 256, 0, stream>>>(Wv, WqkvT, 512, 512, 1024, 786432);
    wtrans_kernel<<<dim3(16, 16, 4), 256, 0, stream>>>(Wo, WoT, 512, 512, 0, 262144);
    wtrans_kernel<<<dim3(64, 16, 4), 256, 0, stream>>>(W1, W1T, 512, 2048, 0, 1048576);
    wtrans_kernel<<<dim3(16, 64, 4), 256, 0, stream>>>(W2, W2T, 2048, 512, 0, 1048576);

    add_pos_kernel<<<(NTOK * DM / 4) / 256, 256, 0, stream>>>(x_in, x);

    dim3 gQKV(QKVD / 128, NTOK / 128, 1);    // (12, 64)  768 blocks
    dim3 gProj(DM / 128, NTOK / 128, 2);     // (4, 64, 2)  512 blocks, split-K
    dim3 gFF1(DFF / 128, NTOK / 128, 1);     // (16, 64)  1024 blocks
    dim3 gFF2(DM / 128, NTOK / 128, 4);      // (4, 64, 4)  1024 blocks, split-K
    dim3 gAttn(SEQ / 64, NH, NB);            // (16, 8, 8)
    dim3 gVtr(16, 32, 8);

    for (int l = 0; l < NLAYER; l++) {
        const size_t wOff   = (size_t)l * 262144;
        const size_t wqkvOff= (size_t)l * 786432;
        const size_t w1Off  = (size_t)l * 1048576;

        ln_kernel<<<NTOK / 4, 256, 0, stream>>>(x, ln1g + l * DM, ln1b + l * DM, hb);
        gemm_bf16<0, 1><<<gQKV, 256, 0, stream>>>(hb, WqkvT + wqkvOff, nullptr, qkv,
                                                  NTOK, QKVD, DM);
        vtrans_kernel<<<gVtr, 256, 0, stream>>>(qkv, vTb);
        attn_mfma<<<gAttn, 256, 0, stream>>>(qkv, vTb, mask, ob);
        gemm_bf16<1, 2><<<gProj, 256, 0, stream>>>(ob, WoT + wOff, nullptr, x,
                                                   NTOK, DM, DM);
        ln_kernel<<<NTOK / 4, 256, 0, stream>>>(x, ln2g + l * DM, ln2b + l * DM, hb);
        gemm_bf16<2, 1><<<gFF1, 256, 0, stream>>>(hb, W1T + w1Off, b1 + (size_t)l * DFF,
                                                  f1b, NTOK, DFF, DM);
        gemm_bf16<3, 4><<<gFF2, 256, 0, stream>>>(f1b, W2T + w1Off, b2 + (size_t)l * DM,
                                                  x, NTOK, DM, DFF);
    }
}

// Round 6
// 1114.831 us; speedup vs baseline: 1.0747x; 1.0747x over previous
//
#include <hip/hip_runtime.h>
#include <math.h>

// Problem constants
#define NB 8
#define SEQ 1024
#define DM 512
#define NH 8
#define HDIM 64
#define DFF 2048
#define NLAYER 4
#define NTOK (NB * SEQ)   // 8192
#define QKVD 1536         // fused q|k|v row width

typedef __attribute__((ext_vector_type(8))) short bf16x8;
typedef __attribute__((ext_vector_type(4))) float f32x4;

__device__ __forceinline__ ushort f2bf(float f) {
    union { float f; unsigned u; } v; v.f = f;
    unsigned r = (v.u + 0x7FFF + ((v.u >> 16) & 1)) >> 16;  // RNE
    return (ushort)r;
}

// async global->LDS, 16B per lane (LDS dest must be wave-uniform base + lane*16)
__device__ __forceinline__ void async16(const void* g, void* l) {
    __builtin_amdgcn_global_load_lds(
        (const __attribute__((address_space(1))) unsigned int*)g,
        (__attribute__((address_space(3))) unsigned int*)l, 16, 0, 0);
}

// ---------------------------------------------------------------------------
// Positional encoding add
// ---------------------------------------------------------------------------
__global__ __launch_bounds__(256) void add_pos_kernel(const float* __restrict__ x,
                                                      float* __restrict__ out) {
    int idx4 = blockIdx.x * blockDim.x + threadIdx.x;
    int base = idx4 * 4;
    int d = base & (DM - 1);
    int s = (base >> 9) & (SEQ - 1);
    float4 v = *(const float4*)&x[base];
    float r[4] = {v.x, v.y, v.z, v.w};
#pragma unroll
    for (int i = 0; i < 4; i++) {
        int dd = d + i;
        float pe;
        if (dd < 256) {
            float inv = powf(10000.0f, 2.0f * (float)dd / 512.0f);
            pe = sinf((float)s / inv);
        } else {
            float inv = powf(10000.0f, 2.0f * (float)(dd - 256) / 512.0f);
            pe = cosf((float)s / inv);
        }
        r[i] += pe;
    }
    *(float4*)&out[base] = make_float4(r[0], r[1], r[2], r[3]);
}

// ---------------------------------------------------------------------------
// Weight convert+transpose: src fp32 [L][K][N] -> dst bf16 rows at
// dst + l*layerStride + (rowOff + n)*K + k
// ---------------------------------------------------------------------------
__global__ __launch_bounds__(256) void wtrans_kernel(const float* __restrict__ src,
                                                     ushort* __restrict__ dst,
                                                     int K, int N, int rowOff,
                                                     int layerStride) {
    __shared__ float tile[32][36];
    int l = blockIdx.z;
    int kb = blockIdx.y * 32, nb = blockIdx.x * 32;
    const float* s = src + (size_t)l * K * N;
    ushort* d = dst + (size_t)l * layerStride;
    int r = threadIdx.x >> 3, c4 = (threadIdx.x & 7) * 4;
    float4 v = *(const float4*)&s[(size_t)(kb + r) * N + nb + c4];
    *(float4*)&tile[r][c4] = v;
    __syncthreads();
    ushort4 o;
    o.x = f2bf(tile[c4 + 0][r]);
    o.y = f2bf(tile[c4 + 1][r]);
    o.z = f2bf(tile[c4 + 2][r]);
    o.w = f2bf(tile[c4 + 3][r]);
    *(ushort4*)&d[(size_t)(rowOff + nb + r) * K + kb + c4] = o;
}

// ---------------------------------------------------------------------------
// bf16 transpose of V slice of qkv: qkv[b*SEQ+s][1024+c] -> vT[b][c][s]
// ---------------------------------------------------------------------------
__global__ __launch_bounds__(256) void vtrans_kernel(const ushort* __restrict__ qkv,
                                                     ushort* __restrict__ vT) {
    __shared__ ushort tile[32][36];
    int b = blockIdx.z;
    int s0 = blockIdx.y * 32, c0 = blockIdx.x * 32;
    int r = threadIdx.x >> 3, q4 = (threadIdx.x & 7) * 4;
    *(ushort4*)&tile[r][q4] =
        *(const ushort4*)&qkv[(size_t)(b * SEQ + s0 + r) * QKVD + 1024 + c0 + q4];
    __syncthreads();
    ushort4 o;
    o.x = tile[q4 + 0][r];
    o.y = tile[q4 + 1][r];
    o.z = tile[q4 + 2][r];
    o.w = tile[q4 + 3][r];
    *(ushort4*)&vT[(size_t)(b * DM + c0 + r) * SEQ + s0 + q4] = o;
}

// ---------------------------------------------------------------------------
// LayerNorm fp32 in -> bf16 out. One wave per row, 4 rows/block.
// ---------------------------------------------------------------------------
__global__ __launch_bounds__(256) void ln_kernel(const float* __restrict__ x,
                                                 const float* __restrict__ g,
                                                 const float* __restrict__ bta,
                                                 ushort* __restrict__ out) {
    int w = threadIdx.x >> 6;
    int lane = threadIdx.x & 63;
    size_t row = (size_t)blockIdx.x * 4 + w;
    const float* xr = x + row * DM;
    float4 v0 = *(const float4*)&xr[lane * 4];
    float4 v1 = *(const float4*)&xr[256 + lane * 4];
    float sum = v0.x + v0.y + v0.z + v0.w + v1.x + v1.y + v1.z + v1.w;
#pragma unroll
    for (int off = 32; off > 0; off >>= 1) sum += __shfl_xor(sum, off, 64);
    float mu = sum * (1.0f / 512.0f);
    float d0[8] = {v0.x - mu, v0.y - mu, v0.z - mu, v0.w - mu,
                   v1.x - mu, v1.y - mu, v1.z - mu, v1.w - mu};
    float sq = 0.0f;
#pragma unroll
    for (int i = 0; i < 8; i++) sq = fmaf(d0[i], d0[i], sq);
#pragma unroll
    for (int off = 32; off > 0; off >>= 1) sq += __shfl_xor(sq, off, 64);
    float rs = rsqrtf(sq * (1.0f / 512.0f) + 1e-3f);
    float4 g0 = *(const float4*)&g[lane * 4];
    float4 g1 = *(const float4*)&g[256 + lane * 4];
    float4 b0 = *(const float4*)&bta[lane * 4];
    float4 b1 = *(const float4*)&bta[256 + lane * 4];
    ushort* orow = out + row * DM;
    ushort4 o0, o1;
    o0.x = f2bf(fmaf(d0[0] * rs, g0.x, b0.x));
    o0.y = f2bf(fmaf(d0[1] * rs, g0.y, b0.y));
    o0.z = f2bf(fmaf(d0[2] * rs, g0.z, b0.z));
    o0.w = f2bf(fmaf(d0[3] * rs, g0.w, b0.w));
    o1.x = f2bf(fmaf(d0[4] * rs, g1.x, b1.x));
    o1.y = f2bf(fmaf(d0[5] * rs, g1.y, b1.y));
    o1.z = f2bf(fmaf(d0[6] * rs, g1.z, b1.z));
    o1.w = f2bf(fmaf(d0[7] * rs, g1.w, b1.w));
    *(ushort4*)&orow[lane * 4] = o0;
    *(ushort4*)&orow[256 + lane * 4] = o1;
}

// ---------------------------------------------------------------------------
// bf16 MFMA GEMM. Tile 128x128, BK=64, 4 waves, double-buffered LDS:
// next-tile global_load_lds issued right after the barrier, drained at the
// NEXT barrier -> every load has a full compute phase in flight.
// Chunk-major LDS [kc][row] (conflict-free). XCD swizzle: the gridDim.x
// N-blocks of an M-row are placed on one XCD (dispatch f%8) so A-tiles are
// L2-shared instead of re-fetched from HBM.
// MODE: 0 = bf16 store; 1 = fp32 +=; 2 = bias+relu -> bf16; 3 = bias + fp32 +=
// ---------------------------------------------------------------------------
template <int MODE>
__global__ __launch_bounds__(256) void gemm_bf16(const ushort* __restrict__ A,
                                                 const ushort* __restrict__ Bt,
                                                 const float* __restrict__ bias,
                                                 void* __restrict__ Cv,
                                                 int M, int N, int K) {
    __shared__ __align__(16) ushort As[2][128 * 64];
    __shared__ __align__(16) ushort Bs[2][128 * 64];
    const int tid = threadIdx.x;
    const int lane = tid & 63;
    const int w = tid >> 6;

    // XCD-colocation swizzle (requires gridDim.y % 8 == 0)
    const int f = blockIdx.y * gridDim.x + blockIdx.x;
    const int gx = gridDim.x;
    const int rows_per_xcd = gridDim.y >> 3;
    const int xcd = f & 7;
    const int kf = f >> 3;
    const int n0 = (kf % gx) * 128;
    const int m0 = (xcd * rows_per_xcd + kf / gx) * 128;

    const int wm = (w >> 1) * 64, wn = (w & 1) * 64;
    const int fm = lane & 15, fq = lane >> 4;

    f32x4 acc[4][4] = {};

    const int nst = K >> 6;  // BK = 64
    // prologue: stage tile 0 into buffer 0
#pragma unroll
    for (int u = 0; u < 4; u++) {
        int s = u * 256 + tid;              // 16B chunk id, 0..1023
        int c = s >> 7, row = s & 127;      // kc 0..7, row 0..127
        async16(&A[(size_t)(m0 + row) * K + c * 8], (char*)As[0] + s * 16);
        async16(&Bt[(size_t)(n0 + row) * K + c * 8], (char*)Bs[0] + s * 16);
    }

    for (int st = 0; st < nst; st++) {
        __syncthreads();  // drains the loads issued one stage ago
        if (st + 1 < nst) {
            int kt = (st + 1) << 6;
            int nb = (st + 1) & 1;
#pragma unroll
            for (int u = 0; u < 4; u++) {
                int s = u * 256 + tid;
                int c = s >> 7, row = s & 127;
                async16(&A[(size_t)(m0 + row) * K + kt + c * 8], (char*)As[nb] + s * 16);
                async16(&Bt[(size_t)(n0 + row) * K + kt + c * 8], (char*)Bs[nb] + s * 16);
            }
        }
        const ushort* Ab = As[st & 1];
        const ushort* Bb = Bs[st & 1];
#pragma unroll
        for (int kk = 0; kk < 2; kk++) {
            bf16x8 af[4], bfr[4];
#pragma unroll
            for (int i = 0; i < 4; i++)
                af[i] = *(const bf16x8*)&Ab[((kk * 4 + fq) * 128 + wm + i * 16 + fm) * 8];
#pragma unroll
            for (int j = 0; j < 4; j++)
                bfr[j] = *(const bf16x8*)&Bb[((kk * 4 + fq) * 128 + wn + j * 16 + fm) * 8];
#pragma unroll
            for (int i = 0; i < 4; i++)
#pragma unroll
                for (int j = 0; j < 4; j++)
                    acc[i][j] = __builtin_amdgcn_mfma_f32_16x16x32_bf16(
                        af[i], bfr[j], acc[i][j], 0, 0, 0);
        }
    }

#pragma unroll
    for (int i = 0; i < 4; i++) {
#pragma unroll
        for (int j = 0; j < 4; j++) {
            int col = n0 + wn + j * 16 + fm;
#pragma unroll
            for (int r = 0; r < 4; r++) {
                int row = m0 + wm + i * 16 + fq * 4 + r;
                float vv = acc[i][j][r];
                if constexpr (MODE == 0) {
                    ((ushort*)Cv)[(size_t)row * N + col] = f2bf(vv);
                } else if constexpr (MODE == 1) {
                    float* C = (float*)Cv;
                    C[(size_t)row * N + col] += vv;
                } else if constexpr (MODE == 2) {
                    vv += bias[col];
                    vv = fmaxf(vv, 0.0f);
                    ((ushort*)Cv)[(size_t)row * N + col] = f2bf(vv);
                } else {
                    float* C = (float*)Cv;
                    C[(size_t)row * N + col] += vv + bias[col];
                }
            }
        }
    }
}

// ---------------------------------------------------------------------------
// Flash attention, S^T formulation (round-3 version, unchanged).
// ---------------------------------------------------------------------------
__global__ __launch_bounds__(256) void attn_mfma(const ushort* __restrict__ QKV,
                                                 const ushort* __restrict__ Vt,
                                                 const int* __restrict__ mask,
                                                 ushort* __restrict__ O) {
    __shared__ __align__(16) ushort Kt[64 * 64];
    __shared__ __align__(16) ushort Vs[64 * 64];
    __shared__ __align__(16) ushort ps[4][16 * 72];  // per-wave P^T [q][key], stride 72
    __shared__ float mskf[64];

    const int tid = threadIdx.x, lane = tid & 63, w = tid >> 6;
    const int h = blockIdx.y, b = blockIdx.z;
    const int q0 = blockIdx.x * 64 + w * 16;
    const int fm = lane & 15, fq = lane >> 4;
    ushort* pw = &ps[w][0];

    // Q as B-fragment: lane: n = q0+fm, k = kk*32 + fq*8 + j
    bf16x8 qf[2];
#pragma unroll
    for (int kk = 0; kk < 2; kk++)
        qf[kk] = *(const bf16x8*)&QKV[(size_t)(b * SEQ + q0 + fm) * QKVD + h * HDIM +
                                      kk * 32 + fq * 8];

    f32x4 oacc[4] = {};   // O^T: col = q (fm), rows dim = nt*16 + fq*4 + r
    float mrow = -INFINITY, lrow = 0.0f;

    for (int j0 = 0; j0 < SEQ; j0 += 64) {
        __syncthreads();
#pragma unroll
        for (int u = 0; u < 2; u++) {
            int ch = tid + u * 256;            // 0..511
            int rrow = ch >> 3, c = ch & 7;
            const ushort* gk = &QKV[(size_t)(b * SEQ + j0 + rrow) * QKVD + 512 +
                                    h * HDIM + c * 8];
            *(uint4*)((char*)Kt + (rrow * 8 + (c ^ (rrow & 7))) * 16) = *(const uint4*)gk;
            const ushort* gv = &Vt[(size_t)((b * NH + h) * HDIM + rrow) * SEQ + j0 + c * 8];
            *(uint4*)((char*)Vs + (rrow * 8 + (c ^ (rrow & 7))) * 16) = *(const uint4*)gv;
        }
        if (tid < 64) mskf[tid] = mask[b * SEQ + j0 + tid] ? 1.0f : 0.0f;
        __syncthreads();

        // ---- S^T = K Q^T : lane holds q-col fm, keys nt*16 + fq*4 + r ----
        f32x4 sc[4] = {};
#pragma unroll
        for (int nt = 0; nt < 4; nt++) {
            int key = nt * 16 + fm;
#pragma unroll
            for (int kk = 0; kk < 2; kk++) {
                bf16x8 kf = *(const bf16x8*)((char*)Kt +
                            (key * 8 + ((kk * 4 + fq) ^ (key & 7))) * 16);
                sc[nt] = __builtin_amdgcn_mfma_f32_16x16x32_bf16(kf, qf[kk], sc[nt], 0, 0, 0);
            }
        }

        // ---- online softmax over the lane's 16 keys ----
        float sv[4][4];
        float mx = -INFINITY;
#pragma unroll
        for (int nt = 0; nt < 4; nt++)
#pragma unroll
            for (int r = 0; r < 4; r++) {
                sv[nt][r] = sc[nt][r] * 0.125f;
                mx = fmaxf(mx, sv[nt][r]);
            }
        mx = fmaxf(mx, __shfl_xor(mx, 16));
        mx = fmaxf(mx, __shfl_xor(mx, 32));
        float mn = fmaxf(mrow, mx);
        float alpha = __expf(mrow - mn);
        mrow = mn;

        float ls = 0.0f;
#pragma unroll
        for (int nt = 0; nt < 4; nt++) {
            f32x4 mv = *(const f32x4*)&mskf[nt * 16 + fq * 4];
#pragma unroll
            for (int r = 0; r < 4; r++) {
                float p = __expf(sv[nt][r] - mn) * mv[r];
                sv[nt][r] = p;
                ls += p;
            }
        }
        ls += __shfl_xor(ls, 16);
        ls += __shfl_xor(ls, 32);
        lrow = lrow * alpha + ls;

        // ---- P^T to per-wave LDS: pw[q=fm][key], trunc-to-bf16 packed ----
#pragma unroll
        for (int nt = 0; nt < 4; nt++) {
            union { float f; unsigned u; } a0, a1, a2, a3;
            a0.f = sv[nt][0]; a1.f = sv[nt][1]; a2.f = sv[nt][2]; a3.f = sv[nt][3];
            unsigned d0 = (a0.u >> 16) | (a1.u & 0xFFFF0000u);
            unsigned d1 = (a2.u >> 16) | (a3.u & 0xFFFF0000u);
            *(uint2*)&pw[fm * 72 + nt * 16 + fq * 4] = make_uint2(d0, d1);
        }

        // rescale O accumulator (alpha is per-lane scalar)
#pragma unroll
        for (int nt = 0; nt < 4; nt++)
#pragma unroll
            for (int r = 0; r < 4; r++) oacc[nt][r] *= alpha;

        // ---- O^T += V^T P^T ----
#pragma unroll
        for (int kk = 0; kk < 2; kk++) {
            bf16x8 pf = *(const bf16x8*)&pw[fm * 72 + kk * 32 + fq * 8];
#pragma unroll
            for (int nt = 0; nt < 4; nt++) {
                int dim = nt * 16 + fm;
                bf16x8 vf = *(const bf16x8*)((char*)Vs +
                            (dim * 8 + ((kk * 4 + fq) ^ (dim & 7))) * 16);
                oacc[nt] = __builtin_amdgcn_mfma_f32_16x16x32_bf16(vf, pf, oacc[nt], 0, 0, 0);
            }
        }
    }

    float inv = 1.0f / lrow;
#pragma unroll
    for (int nt = 0; nt < 4; nt++) {
        ushort4 o;
        o.x = f2bf(oacc[nt][0] * inv);
        o.y = f2bf(oacc[nt][1] * inv);
        o.z = f2bf(oacc[nt][2] * inv);
        o.w = f2bf(oacc[nt][3] * inv);
        *(ushort4*)&O[(size_t)(b * SEQ + q0 + fm) * DM + h * HDIM + nt * 16 + fq * 4] = o;
    }
}

// ---------------------------------------------------------------------------
extern "C" void kernel_launch(void* const* d_in, const int* in_sizes, int n_in,
                              void* d_out, int out_size, void* d_ws, size_t ws_size,
                              hipStream_t stream) {
    const float* x_in = (const float*)d_in[0];
    const int* mask   = (const int*)d_in[1];
    const float* Wq   = (const float*)d_in[2];
    const float* Wk   = (const float*)d_in[3];
    const float* Wv   = (const float*)d_in[4];
    const float* Wo   = (const float*)d_in[5];
    const float* ln1g = (const float*)d_in[6];
    const float* ln1b = (const float*)d_in[7];
    const float* ln2g = (const float*)d_in[8];
    const float* ln2b = (const float*)d_in[9];
    const float* W1   = (const float*)d_in[10];
    const float* b1   = (const float*)d_in[11];
    const float* W2   = (const float*)d_in[12];
    const float* b2   = (const float*)d_in[13];

    float* x = (float*)d_out;  // fp32 residual stream
    ushort* wsb = (ushort*)d_ws;
    const size_t U = 1048576;
    ushort* WqkvT = wsb;            // [L][1536][512]  (3U)
    ushort* WoT   = wsb + 3 * U;    // [L][512][512]   (1U)
    ushort* W1T   = wsb + 4 * U;    // [L][2048][512]  (4U)
    ushort* W2T   = wsb + 8 * U;    // [L][512][2048]  (4U)
    ushort* hb    = wsb + 12 * U;   // bf16 [8192][512]
    ushort* qkv   = wsb + 16 * U;   // bf16 [8192][1536] (12U)
    ushort* ob    = wsb + 28 * U;   // bf16 [8192][512]
    ushort* vTb   = wsb + 32 * U;   // bf16 [8][512][1024]
    ushort* f1b   = qkv;            // 16U alias (qkv+ob), dead during FFN

    // Weight convert+transpose (graph-safe: every launch)
    wtrans_kernel<<<dim3(16, 16, 4), 256, 0, stream>>>(Wq, WqkvT, 512, 512, 0, 786432);
    wtrans_kernel<<<dim3(16, 16, 4), 256, 0, stream>>>(Wk, WqkvT, 512, 512, 512, 786432);
    wtrans_kernel<<<dim3(16, 16, 4), 256, 0, stream>>>(Wv, WqkvT, 512, 512, 1024, 786432);
    wtrans_kernel<<<dim3(16, 16, 4), 256, 0, stream>>>(Wo, WoT, 512, 512, 0, 262144);
    wtrans_kernel<<<dim3(64, 16, 4), 256, 0, stream>>>(W1, W1T, 512, 2048, 0, 1048576);
    wtrans_kernel<<<dim3(16, 64, 4), 256, 0, stream>>>(W2, W2T, 2048, 512, 0, 1048576);

    add_pos_kernel<<<(NTOK * DM / 4) / 256, 256, 0, stream>>>(x_in, x);

    dim3 gQKV(QKVD / 128, NTOK / 128);   // (12, 64)  768 blocks
    dim3 gProj(DM / 128, NTOK / 128);    // (4, 64)   256 blocks
    dim3 gFF1(DFF / 128, NTOK / 128);    // (16, 64)  1024 blocks
    dim3 gAttn(SEQ / 64, NH, NB);        // (16, 8, 8)
    dim3 gVtr(16, 32, 8);

    for (int l = 0; l < NLAYER; l++) {
        const size_t wOff   = (size_t)l * 262144;
        const size_t wqkvOff= (size_t)l * 786432;
        const size_t w1Off  = (size_t)l * 1048576;

        ln_kernel<<<NTOK / 4, 256, 0, stream>>>(x, ln1g + l * DM, ln1b + l * DM, hb);
        gemm_bf16<0><<<gQKV, 256, 0, stream>>>(hb, WqkvT + wqkvOff, nullptr, qkv,
                                               NTOK, QKVD, DM);
        vtrans_kernel<<<gVtr, 256, 0, stream>>>(qkv, vTb);
        attn_mfma<<<gAttn, 256, 0, stream>>>(qkv, vTb, mask, ob);
        gemm_bf16<1><<<gProj, 256, 0, stream>>>(ob, WoT + wOff, nullptr, x,
                                                NTOK, DM, DM);
        ln_kernel<<<NTOK / 4, 256, 0, stream>>>(x, ln2g + l * DM, ln2b + l * DM, hb);
        gemm_bf16<2><<<gFF1, 256, 0, stream>>>(hb, W1T + w1Off, b1 + (size_t)l * DFF,
                                               f1b, NTOK, DFF, DM);
        gemm_bf16<3><<<gProj, 256, 0, stream>>>(f1b, W2T + w1Off, b2 + (size_t)l * DM,
                                                x, NTOK, DM, DFF);
    }
}

// Round 7
// 1043.202 us; speedup vs baseline: 1.1485x; 1.0687x over previous
//
#include <hip/hip_runtime.h>
#include <math.h>

// Problem constants
#define NB 8
#define SEQ 1024
#define DM 512
#define NH 8
#define HDIM 64
#define DFF 2048
#define NLAYER 4
#define NTOK (NB * SEQ)   // 8192
#define QKVD 1536         // fused q|k|v row width

typedef __attribute__((ext_vector_type(8))) short bf16x8;
typedef __attribute__((ext_vector_type(4))) float f32x4;

__device__ __forceinline__ ushort f2bf(float f) {
    union { float f; unsigned u; } v; v.f = f;
    unsigned r = (v.u + 0x7FFF + ((v.u >> 16) & 1)) >> 16;  // RNE
    return (ushort)r;
}

// async global->LDS, 16B per lane (LDS dest must be wave-uniform base + lane*16)
__device__ __forceinline__ void async16(const void* g, void* l) {
    __builtin_amdgcn_global_load_lds(
        (const __attribute__((address_space(1))) unsigned int*)g,
        (__attribute__((address_space(3))) unsigned int*)l, 16, 0, 0);
}

// ---------------------------------------------------------------------------
// Positional encoding add
// ---------------------------------------------------------------------------
__global__ __launch_bounds__(256) void add_pos_kernel(const float* __restrict__ x,
                                                      float* __restrict__ out) {
    int idx4 = blockIdx.x * blockDim.x + threadIdx.x;
    int base = idx4 * 4;
    int d = base & (DM - 1);
    int s = (base >> 9) & (SEQ - 1);
    float4 v = *(const float4*)&x[base];
    float r[4] = {v.x, v.y, v.z, v.w};
#pragma unroll
    for (int i = 0; i < 4; i++) {
        int dd = d + i;
        float pe;
        if (dd < 256) {
            float inv = powf(10000.0f, 2.0f * (float)dd / 512.0f);
            pe = sinf((float)s / inv);
        } else {
            float inv = powf(10000.0f, 2.0f * (float)(dd - 256) / 512.0f);
            pe = cosf((float)s / inv);
        }
        r[i] += pe;
    }
    *(float4*)&out[base] = make_float4(r[0], r[1], r[2], r[3]);
}

// ---------------------------------------------------------------------------
// Weight convert+transpose: src fp32 [L][K][N] -> dst bf16 rows at
// dst + l*layerStride + (rowOff + n)*K + k
// ---------------------------------------------------------------------------
__global__ __launch_bounds__(256) void wtrans_kernel(const float* __restrict__ src,
                                                     ushort* __restrict__ dst,
                                                     int K, int N, int rowOff,
                                                     int layerStride) {
    __shared__ float tile[32][36];
    int l = blockIdx.z;
    int kb = blockIdx.y * 32, nb = blockIdx.x * 32;
    const float* s = src + (size_t)l * K * N;
    ushort* d = dst + (size_t)l * layerStride;
    int r = threadIdx.x >> 3, c4 = (threadIdx.x & 7) * 4;
    float4 v = *(const float4*)&s[(size_t)(kb + r) * N + nb + c4];
    *(float4*)&tile[r][c4] = v;
    __syncthreads();
    ushort4 o;
    o.x = f2bf(tile[c4 + 0][r]);
    o.y = f2bf(tile[c4 + 1][r]);
    o.z = f2bf(tile[c4 + 2][r]);
    o.w = f2bf(tile[c4 + 3][r]);
    *(ushort4*)&d[(size_t)(rowOff + nb + r) * K + kb + c4] = o;
}

// ---------------------------------------------------------------------------
// bf16 transpose of V slice of qkv: qkv[b*SEQ+s][1024+c] -> vT[b][c][s]
// ---------------------------------------------------------------------------
__global__ __launch_bounds__(256) void vtrans_kernel(const ushort* __restrict__ qkv,
                                                     ushort* __restrict__ vT) {
    __shared__ ushort tile[32][36];
    int b = blockIdx.z;
    int s0 = blockIdx.y * 32, c0 = blockIdx.x * 32;
    int r = threadIdx.x >> 3, q4 = (threadIdx.x & 7) * 4;
    *(ushort4*)&tile[r][q4] =
        *(const ushort4*)&qkv[(size_t)(b * SEQ + s0 + r) * QKVD + 1024 + c0 + q4];
    __syncthreads();
    ushort4 o;
    o.x = tile[q4 + 0][r];
    o.y = tile[q4 + 1][r];
    o.z = tile[q4 + 2][r];
    o.w = tile[q4 + 3][r];
    *(ushort4*)&vT[(size_t)(b * DM + c0 + r) * SEQ + s0 + q4] = o;
}

// ---------------------------------------------------------------------------
// LayerNorm fp32 in -> bf16 out. One wave per row, 4 rows/block.
// ---------------------------------------------------------------------------
__global__ __launch_bounds__(256) void ln_kernel(const float* __restrict__ x,
                                                 const float* __restrict__ g,
                                                 const float* __restrict__ bta,
                                                 ushort* __restrict__ out) {
    int w = threadIdx.x >> 6;
    int lane = threadIdx.x & 63;
    size_t row = (size_t)blockIdx.x * 4 + w;
    const float* xr = x + row * DM;
    float4 v0 = *(const float4*)&xr[lane * 4];
    float4 v1 = *(const float4*)&xr[256 + lane * 4];
    float sum = v0.x + v0.y + v0.z + v0.w + v1.x + v1.y + v1.z + v1.w;
#pragma unroll
    for (int off = 32; off > 0; off >>= 1) sum += __shfl_xor(sum, off, 64);
    float mu = sum * (1.0f / 512.0f);
    float d0[8] = {v0.x - mu, v0.y - mu, v0.z - mu, v0.w - mu,
                   v1.x - mu, v1.y - mu, v1.z - mu, v1.w - mu};
    float sq = 0.0f;
#pragma unroll
    for (int i = 0; i < 8; i++) sq = fmaf(d0[i], d0[i], sq);
#pragma unroll
    for (int off = 32; off > 0; off >>= 1) sq += __shfl_xor(sq, off, 64);
    float rs = rsqrtf(sq * (1.0f / 512.0f) + 1e-3f);
    float4 g0 = *(const float4*)&g[lane * 4];
    float4 g1 = *(const float4*)&g[256 + lane * 4];
    float4 b0 = *(const float4*)&bta[lane * 4];
    float4 b1 = *(const float4*)&bta[256 + lane * 4];
    ushort* orow = out + row * DM;
    ushort4 o0, o1;
    o0.x = f2bf(fmaf(d0[0] * rs, g0.x, b0.x));
    o0.y = f2bf(fmaf(d0[1] * rs, g0.y, b0.y));
    o0.z = f2bf(fmaf(d0[2] * rs, g0.z, b0.z));
    o0.w = f2bf(fmaf(d0[3] * rs, g0.w, b0.w));
    o1.x = f2bf(fmaf(d0[4] * rs, g1.x, b1.x));
    o1.y = f2bf(fmaf(d0[5] * rs, g1.y, b1.y));
    o1.z = f2bf(fmaf(d0[6] * rs, g1.z, b1.z));
    o1.w = f2bf(fmaf(d0[7] * rs, g1.w, b1.w));
    *(ushort4*)&orow[lane * 4] = o0;
    *(ushort4*)&orow[256 + lane * 4] = o1;
}

// ---------------------------------------------------------------------------
// bf16 MFMA GEMM. Tile 128(M) x TN(N), BK=32, single-buffered, 4 waves.
// Chunk-major LDS [kc][row] -> conflict-free fragment reads (verified R4).
// XCD-colocation swizzle: all N-blocks of an M-row land on one XCD so the
// A panel is fetched from HBM once per XCD and L2-shared (verified R6).
// TN=64 doubles blocks/CU for the N=512 GEMMs; with colocation this does
// NOT multiply HBM A-fetch (the R4 failure mode).
// MODE: 0 = bf16 store; 1 = fp32 +=; 2 = bias+relu -> bf16; 3 = bias + fp32 +=
// ---------------------------------------------------------------------------
template <int MODE, int TN>
__global__ __launch_bounds__(256) void gemm_bf16(const ushort* __restrict__ A,
                                                 const ushort* __restrict__ Bt,
                                                 const float* __restrict__ bias,
                                                 void* __restrict__ Cv,
                                                 int M, int N, int K) {
    constexpr int NJ = TN / 32;
    __shared__ __align__(16) ushort As[128 * 32];
    __shared__ __align__(16) ushort Bs[TN * 32];
    const int tid = threadIdx.x;
    const int lane = tid & 63;
    const int w = tid >> 6;

    // XCD-colocation swizzle (requires gridDim.y % 8 == 0)
    const int f = blockIdx.y * gridDim.x + blockIdx.x;
    const int gx = gridDim.x;
    const int rows_per_xcd = gridDim.y >> 3;
    const int xcd = f & 7;
    const int kf = f >> 3;
    const int n0 = (kf % gx) * TN;
    const int m0 = (xcd * rows_per_xcd + kf / gx) * 128;

    const int wm = (w >> 1) * 64, wn = (w & 1) * (TN / 2);
    const int fm = lane & 15, fq = lane >> 4;

    f32x4 acc[4][NJ] = {};

    for (int kt = 0; kt < K; kt += 32) {
        __syncthreads();
        // A tile: 512 chunks, chunk-major slot = kc*128 + row
#pragma unroll
        for (int u = 0; u < 2; u++) {
            int s = (w * 2 + u) * 64 + lane;
            int c = s >> 7, row = s & 127;
            async16(&A[(size_t)(m0 + row) * K + kt + c * 8], (char*)As + s * 16);
        }
        // B tile: TN*4 chunks, chunk-major slot = kc*TN + row
        if constexpr (TN == 128) {
#pragma unroll
            for (int u = 0; u < 2; u++) {
                int s = (w * 2 + u) * 64 + lane;
                int c = s >> 7, row = s & 127;
                async16(&Bt[(size_t)(n0 + row) * K + kt + c * 8], (char*)Bs + s * 16);
            }
        } else {
            int s = w * 64 + lane;            // 0..255
            int c = s >> 6, row = s & 63;
            async16(&Bt[(size_t)(n0 + row) * K + kt + c * 8], (char*)Bs + s * 16);
        }
        __syncthreads();
        bf16x8 af[4], bfr[NJ];
#pragma unroll
        for (int i = 0; i < 4; i++)
            af[i] = *(const bf16x8*)&As[(fq * 128 + wm + i * 16 + fm) * 8];
#pragma unroll
        for (int j = 0; j < NJ; j++)
            bfr[j] = *(const bf16x8*)&Bs[(fq * TN + wn + j * 16 + fm) * 8];
#pragma unroll
        for (int i = 0; i < 4; i++)
#pragma unroll
            for (int j = 0; j < NJ; j++)
                acc[i][j] = __builtin_amdgcn_mfma_f32_16x16x32_bf16(
                    af[i], bfr[j], acc[i][j], 0, 0, 0);
    }

#pragma unroll
    for (int i = 0; i < 4; i++) {
#pragma unroll
        for (int j = 0; j < NJ; j++) {
            int col = n0 + wn + j * 16 + fm;
#pragma unroll
            for (int r = 0; r < 4; r++) {
                int row = m0 + wm + i * 16 + fq * 4 + r;
                float vv = acc[i][j][r];
                if constexpr (MODE == 0) {
                    ((ushort*)Cv)[(size_t)row * N + col] = f2bf(vv);
                } else if constexpr (MODE == 1) {
                    float* C = (float*)Cv;
                    C[(size_t)row * N + col] += vv;
                } else if constexpr (MODE == 2) {
                    vv += bias[col];
                    vv = fmaxf(vv, 0.0f);
                    ((ushort*)Cv)[(size_t)row * N + col] = f2bf(vv);
                } else {
                    float* C = (float*)Cv;
                    C[(size_t)row * N + col] += vv + bias[col];
                }
            }
        }
    }
}

// ---------------------------------------------------------------------------
// Flash attention, S^T formulation (round-3 version, unchanged).
// ---------------------------------------------------------------------------
__global__ __launch_bounds__(256) void attn_mfma(const ushort* __restrict__ QKV,
                                                 const ushort* __restrict__ Vt,
                                                 const int* __restrict__ mask,
                                                 ushort* __restrict__ O) {
    __shared__ __align__(16) ushort Kt[64 * 64];
    __shared__ __align__(16) ushort Vs[64 * 64];
    __shared__ __align__(16) ushort ps[4][16 * 72];  // per-wave P^T [q][key], stride 72
    __shared__ float mskf[64];

    const int tid = threadIdx.x, lane = tid & 63, w = tid >> 6;
    const int h = blockIdx.y, b = blockIdx.z;
    const int q0 = blockIdx.x * 64 + w * 16;
    const int fm = lane & 15, fq = lane >> 4;
    ushort* pw = &ps[w][0];

    // Q as B-fragment: lane: n = q0+fm, k = kk*32 + fq*8 + j
    bf16x8 qf[2];
#pragma unroll
    for (int kk = 0; kk < 2; kk++)
        qf[kk] = *(const bf16x8*)&QKV[(size_t)(b * SEQ + q0 + fm) * QKVD + h * HDIM +
                                      kk * 32 + fq * 8];

    f32x4 oacc[4] = {};   // O^T: col = q (fm), rows dim = nt*16 + fq*4 + r
    float mrow = -INFINITY, lrow = 0.0f;

    for (int j0 = 0; j0 < SEQ; j0 += 64) {
        __syncthreads();
#pragma unroll
        for (int u = 0; u < 2; u++) {
            int ch = tid + u * 256;            // 0..511
            int rrow = ch >> 3, c = ch & 7;
            const ushort* gk = &QKV[(size_t)(b * SEQ + j0 + rrow) * QKVD + 512 +
                                    h * HDIM + c * 8];
            *(uint4*)((char*)Kt + (rrow * 8 + (c ^ (rrow & 7))) * 16) = *(const uint4*)gk;
            const ushort* gv = &Vt[(size_t)((b * NH + h) * HDIM + rrow) * SEQ + j0 + c * 8];
            *(uint4*)((char*)Vs + (rrow * 8 + (c ^ (rrow & 7))) * 16) = *(const uint4*)gv;
        }
        if (tid < 64) mskf[tid] = mask[b * SEQ + j0 + tid] ? 1.0f : 0.0f;
        __syncthreads();

        // ---- S^T = K Q^T : lane holds q-col fm, keys nt*16 + fq*4 + r ----
        f32x4 sc[4] = {};
#pragma unroll
        for (int nt = 0; nt < 4; nt++) {
            int key = nt * 16 + fm;
#pragma unroll
            for (int kk = 0; kk < 2; kk++) {
                bf16x8 kf = *(const bf16x8*)((char*)Kt +
                            (key * 8 + ((kk * 4 + fq) ^ (key & 7))) * 16);
                sc[nt] = __builtin_amdgcn_mfma_f32_16x16x32_bf16(kf, qf[kk], sc[nt], 0, 0, 0);
            }
        }

        // ---- online softmax over the lane's 16 keys ----
        float sv[4][4];
        float mx = -INFINITY;
#pragma unroll
        for (int nt = 0; nt < 4; nt++)
#pragma unroll
            for (int r = 0; r < 4; r++) {
                sv[nt][r] = sc[nt][r] * 0.125f;
                mx = fmaxf(mx, sv[nt][r]);
            }
        mx = fmaxf(mx, __shfl_xor(mx, 16));
        mx = fmaxf(mx, __shfl_xor(mx, 32));
        float mn = fmaxf(mrow, mx);
        float alpha = __expf(mrow - mn);
        mrow = mn;

        float ls = 0.0f;
#pragma unroll
        for (int nt = 0; nt < 4; nt++) {
            f32x4 mv = *(const f32x4*)&mskf[nt * 16 + fq * 4];
#pragma unroll
            for (int r = 0; r < 4; r++) {
                float p = __expf(sv[nt][r] - mn) * mv[r];
                sv[nt][r] = p;
                ls += p;
            }
        }
        ls += __shfl_xor(ls, 16);
        ls += __shfl_xor(ls, 32);
        lrow = lrow * alpha + ls;

        // ---- P^T to per-wave LDS: pw[q=fm][key], trunc-to-bf16 packed ----
#pragma unroll
        for (int nt = 0; nt < 4; nt++) {
            union { float f; unsigned u; } a0, a1, a2, a3;
            a0.f = sv[nt][0]; a1.f = sv[nt][1]; a2.f = sv[nt][2]; a3.f = sv[nt][3];
            unsigned d0 = (a0.u >> 16) | (a1.u & 0xFFFF0000u);
            unsigned d1 = (a2.u >> 16) | (a3.u & 0xFFFF0000u);
            *(uint2*)&pw[fm * 72 + nt * 16 + fq * 4] = make_uint2(d0, d1);
        }

        // rescale O accumulator (alpha is per-lane scalar)
#pragma unroll
        for (int nt = 0; nt < 4; nt++)
#pragma unroll
            for (int r = 0; r < 4; r++) oacc[nt][r] *= alpha;

        // ---- O^T += V^T P^T ----
#pragma unroll
        for (int kk = 0; kk < 2; kk++) {
            bf16x8 pf = *(const bf16x8*)&pw[fm * 72 + kk * 32 + fq * 8];
#pragma unroll
            for (int nt = 0; nt < 4; nt++) {
                int dim = nt * 16 + fm;
                bf16x8 vf = *(const bf16x8*)((char*)Vs +
                            (dim * 8 + ((kk * 4 + fq) ^ (dim & 7))) * 16);
                oacc[nt] = __builtin_amdgcn_mfma_f32_16x16x32_bf16(vf, pf, oacc[nt], 0, 0, 0);
            }
        }
    }

    float inv = 1.0f / lrow;
#pragma unroll
    for (int nt = 0; nt < 4; nt++) {
        ushort4 o;
        o.x = f2bf(oacc[nt][0] * inv);
        o.y = f2bf(oacc[nt][1] * inv);
        o.z = f2bf(oacc[nt][2] * inv);
        o.w = f2bf(oacc[nt][3] * inv);
        *(ushort4*)&O[(size_t)(b * SEQ + q0 + fm) * DM + h * HDIM + nt * 16 + fq * 4] = o;
    }
}

// ---------------------------------------------------------------------------
extern "C" void kernel_launch(void* const* d_in, const int* in_sizes, int n_in,
                              void* d_out, int out_size, void* d_ws, size_t ws_size,
                              hipStream_t stream) {
    const float* x_in = (const float*)d_in[0];
    const int* mask   = (const int*)d_in[1];
    const float* Wq   = (const float*)d_in[2];
    const float* Wk   = (const float*)d_in[3];
    const float* Wv   = (const float*)d_in[4];
    const float* Wo   = (const float*)d_in[5];
    const float* ln1g = (const float*)d_in[6];
    const float* ln1b = (const float*)d_in[7];
    const float* ln2g = (const float*)d_in[8];
    const float* ln2b = (const float*)d_in[9];
    const float* W1   = (const float*)d_in[10];
    const float* b1   = (const float*)d_in[11];
    const float* W2   = (const float*)d_in[12];
    const float* b2   = (const float*)d_in[13];

    float* x = (float*)d_out;  // fp32 residual stream
    ushort* wsb = (ushort*)d_ws;
    const size_t U = 1048576;
    ushort* WqkvT = wsb;            // [L][1536][512]  (3U)
    ushort* WoT   = wsb + 3 * U;    // [L][512][512]   (1U)
    ushort* W1T   = wsb + 4 * U;    // [L][2048][512]  (4U)
    ushort* W2T   = wsb + 8 * U;    // [L][512][2048]  (4U)
    ushort* hb    = wsb + 12 * U;   // bf16 [8192][512]
    ushort* qkv   = wsb + 16 * U;   // bf16 [8192][1536] (12U)
    ushort* ob    = wsb + 28 * U;   // bf16 [8192][512]
    ushort* vTb   = wsb + 32 * U;   // bf16 [8][512][1024]
    ushort* f1b   = qkv;            // 16U alias (qkv+ob), dead during FFN

    // Weight convert+transpose (graph-safe: every launch)
    wtrans_kernel<<<dim3(16, 16, 4), 256, 0, stream>>>(Wq, WqkvT, 512, 512, 0, 786432);
    wtrans_kernel<<<dim3(16, 16, 4), 256, 0, stream>>>(Wk, WqkvT, 512, 512, 512, 786432);
    wtrans_kernel<<<dim3(16, 16, 4), 256, 0, stream>>>(Wv, WqkvT, 512, 512, 1024, 786432);
    wtrans_kernel<<<dim3(16, 16, 4), 256, 0, stream>>>(Wo, WoT, 512, 512, 0, 262144);
    wtrans_kernel<<<dim3(64, 16, 4), 256, 0, stream>>>(W1, W1T, 512, 2048, 0, 1048576);
    wtrans_kernel<<<dim3(16, 64, 4), 256, 0, stream>>>(W2, W2T, 2048, 512, 0, 1048576);

    add_pos_kernel<<<(NTOK * DM / 4) / 256, 256, 0, stream>>>(x_in, x);

    dim3 gQKV(QKVD / 128, NTOK / 128);   // (12, 64)  768 blocks, TN=128
    dim3 gProj(DM / 64, NTOK / 128);     // (8, 64)   512 blocks, TN=64
    dim3 gFF1(DFF / 128, NTOK / 128);    // (16, 64)  1024 blocks, TN=128
    dim3 gAttn(SEQ / 64, NH, NB);        // (16, 8, 8)
    dim3 gVtr(16, 32, 8);

    for (int l = 0; l < NLAYER; l++) {
        const size_t wOff   = (size_t)l * 262144;
        const size_t wqkvOff= (size_t)l * 786432;
        const size_t w1Off  = (size_t)l * 1048576;

        ln_kernel<<<NTOK / 4, 256, 0, stream>>>(x, ln1g + l * DM, ln1b + l * DM, hb);
        gemm_bf16<0, 128><<<gQKV, 256, 0, stream>>>(hb, WqkvT + wqkvOff, nullptr, qkv,
                                                    NTOK, QKVD, DM);
        vtrans_kernel<<<gVtr, 256, 0, stream>>>(qkv, vTb);
        attn_mfma<<<gAttn, 256, 0, stream>>>(qkv, vTb, mask, ob);
        gemm_bf16<1, 64><<<gProj, 256, 0, stream>>>(ob, WoT + wOff, nullptr, x,
                                                    NTOK, DM, DM);
        ln_kernel<<<NTOK / 4, 256, 0, stream>>>(x, ln2g + l * DM, ln2b + l * DM, hb);
        gemm_bf16<2, 128><<<gFF1, 256, 0, stream>>>(hb, W1T + w1Off, b1 + (size_t)l * DFF,
                                                    f1b, NTOK, DFF, DM);
        gemm_bf16<3, 64><<<gProj, 256, 0, stream>>>(f1b, W2T + w1Off, b2 + (size_t)l * DM,
                                                    x, NTOK, DM, DFF);
    }
}